// Round 3
// baseline (220.340 us; speedup 1.0000x reference)
//
#include <hip/hip_runtime.h>

#define D_IN    784
#define HDIM    512
#define BATCH_N 1024

// ---- pass decomposition ----
#define NSEG    7
#define SEGLEN  112                    // 7 * 112 = 784
#define TC      4                      // steps per staged chunk (pass 2)
#define NCH2    (SEGLEN / TC)          // 28 chunks per segment

// ---- ws layout (floats) ----
#define WT_FLOATS   ((size_t)D_IN * HDIM)        // 401408
#define CKPT_STRIDE ((size_t)BATCH_N * HDIM)     // 524288 floats per slot
#define CKPT_FLOATS ((size_t)NSEG * CKPT_STRIDE) // 7 slots

__device__ __forceinline__ float relu_(float v) { return fmaxf(v, 0.0f); }
__device__ __forceinline__ float sigmoid_(float v) {
    return __builtin_amdgcn_rcpf(1.0f + __expf(-v));
}

// ---------------------------------------------------------------------------
// Transpose in_W [H][D] -> wT [D][H]
// ---------------------------------------------------------------------------
__global__ __launch_bounds__(256, 1)
void transpose_inW(const float* __restrict__ inW, float* __restrict__ wT) {
    int idx = blockIdx.x * 256 + threadIdx.x;
    if (idx < D_IN * HDIM) {
        int i = idx / HDIM;
        int h = idx - i * HDIM;
        wT[idx] = inW[(size_t)h * D_IN + i];
    }
}

// ---------------------------------------------------------------------------
// Pass 1: per-segment rank-sum  G[k][b][h] = sum_{i in seg k} x[b,i]*wT[i][h]
// written into ckpt slot k+1. Block = 16 rows x one segment; thread owns
// 2 rows x 16 h (h = hc*4 + 128j).
// ---------------------------------------------------------------------------
__global__ __launch_bounds__(256, 4)
void seg_sums(const float* __restrict__ x, const float* __restrict__ wT,
              float* __restrict__ ckpt) {
    const int rt = blockIdx.x;          // row tile (16 rows)
    const int k  = blockIdx.y;          // segment 0..NSEG-2
    const int tid = threadIdx.x;
    const int r2 = tid >> 5;            // 0..7
    const int hc = tid & 31;            // 0..31
    const int r0 = rt * 16 + r2;
    const int r1 = r0 + 8;
    const int i0 = k * SEGLEN;

    float acc0[16], acc1[16];
    #pragma unroll
    for (int j = 0; j < 16; ++j) { acc0[j] = 0.0f; acc1[j] = 0.0f; }

    const float* x0 = x + (size_t)r0 * D_IN + i0;
    const float* x1 = x + (size_t)r1 * D_IN + i0;
    const float* w  = wT + (size_t)i0 * HDIM + hc * 4;

    for (int i = 0; i < SEGLEN; ++i) {
        const float xa = x0[i];
        const float xb = x1[i];
        const float* wr = w + (size_t)i * HDIM;
        #pragma unroll
        for (int j = 0; j < 4; ++j) {
            float4 wv = *(const float4*)(wr + j * 128);
            acc0[4*j+0] = fmaf(xa, wv.x, acc0[4*j+0]);
            acc0[4*j+1] = fmaf(xa, wv.y, acc0[4*j+1]);
            acc0[4*j+2] = fmaf(xa, wv.z, acc0[4*j+2]);
            acc0[4*j+3] = fmaf(xa, wv.w, acc0[4*j+3]);
            acc1[4*j+0] = fmaf(xb, wv.x, acc1[4*j+0]);
            acc1[4*j+1] = fmaf(xb, wv.y, acc1[4*j+1]);
            acc1[4*j+2] = fmaf(xb, wv.z, acc1[4*j+2]);
            acc1[4*j+3] = fmaf(xb, wv.w, acc1[4*j+3]);
        }
    }

    float* g0 = ckpt + (size_t)(k + 1) * CKPT_STRIDE + (size_t)r0 * HDIM + hc * 4;
    float* g1 = ckpt + (size_t)(k + 1) * CKPT_STRIDE + (size_t)r1 * HDIM + hc * 4;
    #pragma unroll
    for (int j = 0; j < 4; ++j) {
        *(float4*)(g0 + j * 128) = make_float4(acc0[4*j+0], acc0[4*j+1], acc0[4*j+2], acc0[4*j+3]);
        *(float4*)(g1 + j * 128) = make_float4(acc1[4*j+0], acc1[4*j+1], acc1[4*j+2], acc1[4*j+3]);
    }
}

// ---------------------------------------------------------------------------
// Pass 1.5: in-place prefix  ckpt[0]=in_b ; ckpt[k]=ckpt[k-1]+G[k-1]
// ---------------------------------------------------------------------------
__global__ __launch_bounds__(256, 4)
void prefix_ck(const float* __restrict__ in_b, float* __restrict__ ckpt) {
    int idx = blockIdx.x * 256 + threadIdx.x;   // 0 .. 1024*128
    int b  = idx >> 7;
    int hq = idx & 127;
    float* p = ckpt + (size_t)b * HDIM + hq * 4;
    float4 cur = *(const float4*)(in_b + hq * 4);
    *(float4*)p = cur;
    #pragma unroll
    for (int k = 1; k < NSEG; ++k) {
        float4 g = *(const float4*)(p + k * CKPT_STRIDE);
        cur.x += g.x; cur.y += g.y; cur.z += g.z; cur.w += g.w;
        *(float4*)(p + k * CKPT_STRIDE) = cur;
    }
}

// ---------------------------------------------------------------------------
// Pass 2: segment scan. Block = 8 rows (8 waves) x one segment.
// Lane l owns hidden units {4l..4l+3} U {256+4l..256+4l+3}.
// Weights double-buffered in LDS via global_load_lds; butterfly reduction.
// ---------------------------------------------------------------------------
__global__ __launch_bounds__(512, 6)
void nade_fwd3(const float* __restrict__ x,
               const float* __restrict__ ckpt,
               const float* __restrict__ hW,
               const float* __restrict__ h_b,
               const float* __restrict__ wT,
               float* __restrict__ out) {
    __shared__ float sbuf[2][2 * TC * HDIM];   // [buf][ hW(2048) | wT(2048) ]

    const int tid = threadIdx.x;
    const int w   = tid >> 6;                  // wave 0..7 -> row within block
    const int l   = tid & 63;
    const int row = blockIdx.x * 8 + w;
    const int k   = blockIdx.y;                // segment
    const int base = k * SEGLEN;

    // init a from checkpoint
    float a[8];
    {
        const float* ap = ckpt + (size_t)k * CKPT_STRIDE + (size_t)row * HDIM;
        float4 a0 = *(const float4*)(ap + 4 * l);
        float4 a1 = *(const float4*)(ap + 256 + 4 * l);
        a[0]=a0.x; a[1]=a0.y; a[2]=a0.z; a[3]=a0.w;
        a[4]=a1.x; a[5]=a1.y; a[6]=a1.z; a[7]=a1.w;
    }

    const float* xrow = x   + (size_t)row * D_IN + base;
    float*       orow = out + (size_t)row * D_IN + base;
    const float* hbp  = h_b + base;

    // stage chunk c into sbuf[buf]: 8 waves x 2KB ; waves 0-3 take hW, 4-7 wT
#define STAGE(buf_, c_) {                                                        \
        const int i0_ = base + (c_) * TC;                                        \
        const float* src_ = (w < 4) ? (hW + (size_t)i0_ * HDIM + w * 512)        \
                                    : (wT + (size_t)i0_ * HDIM + (w - 4) * 512); \
        float* dst_ = &sbuf[buf_][w * 512];                                      \
        __builtin_amdgcn_global_load_lds(                                        \
            (const __attribute__((address_space(1))) void*)(src_ + l * 4),       \
            (__attribute__((address_space(3))) void*)(dst_ + l * 4), 16, 0, 0);  \
        __builtin_amdgcn_global_load_lds(                                        \
            (const __attribute__((address_space(1))) void*)(src_ + 256 + l * 4), \
            (__attribute__((address_space(3))) void*)(dst_ + 256 + l * 4), 16, 0, 0); \
    }

    STAGE(0, 0);
    __syncthreads();   // vmcnt(0) drained by barrier: buf0 ready

    for (int c = 0; c < NCH2; ++c) {
        const int buf = c & 1;
        if (c + 1 < NCH2) STAGE(buf ^ 1, c + 1);

        const float* bh = &sbuf[buf][0];
        const float* bw = &sbuf[buf][2048];

        float4 xv  = *(const float4*)(xrow + c * TC);
        float4 hbv = *(const float4*)(hbp  + c * TC);
        const float xs[4] = {xv.x, xv.y, xv.z, xv.w};
        const float hb[4] = {hbv.x, hbv.y, hbv.z, hbv.w};

        float part[4];
        #pragma unroll
        for (int t = 0; t < TC; ++t) {
            const float* hp = bh + t * HDIM;
            float4 h0 = *(const float4*)(hp + 4 * l);
            float4 h1 = *(const float4*)(hp + 256 + 4 * l);
            float init = (l == 0) ? hb[t] : 0.0f;
            float p0 = fmaf(relu_(a[0]), h0.x, init);
            p0 = fmaf(relu_(a[1]), h0.y, p0);
            p0 = fmaf(relu_(a[2]), h0.z, p0);
            p0 = fmaf(relu_(a[3]), h0.w, p0);
            float p1 = relu_(a[4]) * h1.x;
            p1 = fmaf(relu_(a[5]), h1.y, p1);
            p1 = fmaf(relu_(a[6]), h1.z, p1);
            p1 = fmaf(relu_(a[7]), h1.w, p1);
            part[t] = p0 + p1;

            const float* wp = bw + t * HDIM;
            float4 w0 = *(const float4*)(wp + 4 * l);
            float4 w1 = *(const float4*)(wp + 256 + 4 * l);
            const float xi = xs[t];    // exactly 0.0 or 1.0
            a[0] = fmaf(xi, w0.x, a[0]); a[1] = fmaf(xi, w0.y, a[1]);
            a[2] = fmaf(xi, w0.z, a[2]); a[3] = fmaf(xi, w0.w, a[3]);
            a[4] = fmaf(xi, w1.x, a[4]); a[5] = fmaf(xi, w1.y, a[5]);
            a[6] = fmaf(xi, w1.z, a[6]); a[7] = fmaf(xi, w1.w, a[7]);
        }

        // 4 independent butterflies, pipelined
        #pragma unroll
        for (int s = 1; s < 64; s <<= 1) {
            #pragma unroll
            for (int t = 0; t < TC; ++t)
                part[t] += __shfl_xor(part[t], s, 64);
        }

        if (l == 0) {
            float4 rv = make_float4(sigmoid_(part[0]), sigmoid_(part[1]),
                                    sigmoid_(part[2]), sigmoid_(part[3]));
            *(float4*)(orow + c * TC) = rv;
        }
        __syncthreads();
    }
#undef STAGE
}

// ---------------------------------------------------------------------------
// Fallback (small ws): round-1 kernel, strided in_W reads.
// ---------------------------------------------------------------------------
__global__ __launch_bounds__(64, 1)
void nade_fwd_fallback(const float* __restrict__ x,
                       const float* __restrict__ in_W,
                       const float* __restrict__ in_b,
                       const float* __restrict__ hW,
                       const float* __restrict__ h_b,
                       float* __restrict__ out) {
    const int b  = blockIdx.x;
    const int l  = threadIdx.x;
    const int h0 = l * 8;

    float a[8];
    {
        float4 b0 = *(const float4*)(in_b + h0);
        float4 b1 = *(const float4*)(in_b + h0 + 4);
        a[0]=b0.x; a[1]=b0.y; a[2]=b0.z; a[3]=b0.w;
        a[4]=b1.x; a[5]=b1.y; a[6]=b1.z; a[7]=b1.w;
    }
    const float* xrow = x + (size_t)b * D_IN;
    float* orow = out + (size_t)b * D_IN;

    for (int i = 0; i < D_IN; ++i) {
        const float4 hw0 = *(const float4*)(hW + (size_t)i * HDIM + h0);
        const float4 hw1 = *(const float4*)(hW + (size_t)i * HDIM + h0 + 4);
        float p;
        p = relu_(a[0]) * hw0.x;
        p = fmaf(relu_(a[1]), hw0.y, p);
        p = fmaf(relu_(a[2]), hw0.z, p);
        p = fmaf(relu_(a[3]), hw0.w, p);
        p = fmaf(relu_(a[4]), hw1.x, p);
        p = fmaf(relu_(a[5]), hw1.y, p);
        p = fmaf(relu_(a[6]), hw1.z, p);
        p = fmaf(relu_(a[7]), hw1.w, p);
        #pragma unroll
        for (int s = 1; s < 64; s <<= 1) p += __shfl_xor(p, s, 64);
        if (l == 0) orow[i] = sigmoid_(p + h_b[i]);

        const float xi = xrow[i];
        if (xi != 0.0f) {
            a[0] = fmaf(xi, in_W[(size_t)(h0+0)*D_IN + i], a[0]);
            a[1] = fmaf(xi, in_W[(size_t)(h0+1)*D_IN + i], a[1]);
            a[2] = fmaf(xi, in_W[(size_t)(h0+2)*D_IN + i], a[2]);
            a[3] = fmaf(xi, in_W[(size_t)(h0+3)*D_IN + i], a[3]);
            a[4] = fmaf(xi, in_W[(size_t)(h0+4)*D_IN + i], a[4]);
            a[5] = fmaf(xi, in_W[(size_t)(h0+5)*D_IN + i], a[5]);
            a[6] = fmaf(xi, in_W[(size_t)(h0+6)*D_IN + i], a[6]);
            a[7] = fmaf(xi, in_W[(size_t)(h0+7)*D_IN + i], a[7]);
        }
    }
}

extern "C" void kernel_launch(void* const* d_in, const int* in_sizes, int n_in,
                              void* d_out, int out_size, void* d_ws, size_t ws_size,
                              hipStream_t stream) {
    const float* x    = (const float*)d_in[0];
    const float* in_W = (const float*)d_in[1];
    const float* in_b = (const float*)d_in[2];
    const float* hW   = (const float*)d_in[3];
    const float* h_b  = (const float*)d_in[4];
    float* out = (float*)d_out;

    const size_t need_full = (WT_FLOATS + CKPT_FLOATS) * sizeof(float);   // ~16.3 MB

    if (ws_size >= need_full) {
        float* wT   = (float*)d_ws;
        float* ckpt = wT + WT_FLOATS;

        hipLaunchKernelGGL(transpose_inW,
                           dim3((D_IN * HDIM + 255) / 256), dim3(256), 0, stream,
                           in_W, wT);
        hipLaunchKernelGGL(seg_sums,
                           dim3(BATCH_N / 16, NSEG - 1), dim3(256), 0, stream,
                           x, wT, ckpt);
        hipLaunchKernelGGL(prefix_ck,
                           dim3(BATCH_N * (HDIM / 4) / 256), dim3(256), 0, stream,
                           in_b, ckpt);
        hipLaunchKernelGGL(nade_fwd3,
                           dim3(BATCH_N / 8, NSEG), dim3(512), 0, stream,
                           x, ckpt, hW, h_b, wT, out);
    } else {
        hipLaunchKernelGGL(nade_fwd_fallback,
                           dim3(BATCH_N), dim3(64), 0, stream,
                           x, in_W, in_b, hW, h_b, out);
    }
}